// Round 3
// baseline (503.412 us; speedup 1.0000x reference)
//
#include <hip/hip_runtime.h>

// Problem constants (fixed by setup_inputs)
#define B_    16
#define N_    16384
#define C_    80
#define NC_   (N_ * C_)      // 1310720 per batch
#define TOPN_ 1000
#define CAP_  8192           // candidate buffer per batch (pow2 for bitonic)
#define NB_   128            // fine histogram bins: key>>17 for score in [0.25, 1.0)
#define BINBASE_ 8000        // 0x3E800000 >> 17  (bits(0.25f))

// Workspace layout (bytes). Zero region = [0, ZERO_BYTES)
#define OFF_HIST   0u        // 16*128*4 = 8192
#define OFF_CNT    8192u     // 16*4 (pad 256)
#define ZERO_BYTES 8448u
#define OFF_L      8448u     // 16*4 (pad 256)
#define OFF_VALID  8704u     // 16*16*8 = 2048
#define OFF_CAND   10752u    // 16*8192*8 = 1048576
#define OFF_DET    1059328u  // 16*1024*16 = 262144 (float4)
#define OFF_DETO   1321472u  // 262144 (float4, class-offset boxes)
#define OFF_SCORE  1583616u  // 16*1024*4 = 65536
#define OFF_LAB    1649152u  // 65536
#define OFF_SUP    1714688u  // 16*1024*16*8 = 2097152
// total 3811840 (~3.6 MB)

__device__ __forceinline__ float sigm(float x) { return 1.0f / (1.0f + expf(-x)); }

// ---------------------------------------------------------------------------
// Pass 1: fine histogram of score keys >= 0.25.
// Grid (256, B_) x 256. Block bx owns rows [bx*64, +64) = float4 f in [0,1280).
// 5 independent float4 loads per thread issued before any branch (MLP=5).
// Keys binned with native exp/rcp (<= ~5 ULP error, << 2^17-ULP bin width);
// k_findL compensates with a 1-bin safety margin so exact-count holds.
// ---------------------------------------------------------------------------
__global__ __launch_bounds__(256) void k_hist(const float* __restrict__ cls,
                                              const float* __restrict__ ctr,
                                              unsigned* __restrict__ hist) {
    __shared__ float xh[64];     // raw-cls threshold for score >= 0.25 (conservative)
    __shared__ float sbv[64];    // exact sigmoid(centerness) per row
    __shared__ unsigned lh[NB_];
    const int b = blockIdx.y, bx = blockIdx.x, t = threadIdx.x;
    if (t < 64) {
        float sc = sigm(ctr[b * N_ + bx * 64 + t]);
        sbv[t] = sc;
        float q = 0.25f / sc;
        xh[t] = (q < 1.f) ? (logf(q / (1.f - q)) - 1e-3f) : 3.0e38f;
    }
    if (t < NB_) lh[t] = 0;
    __syncthreads();
    const float4* cb4 = (const float4*)(cls + (size_t)b * NC_ + (size_t)bx * 5120);
    float4 v0 = cb4[t];
    float4 v1 = cb4[256 + t];
    float4 v2 = cb4[512 + t];
    float4 v3 = cb4[768 + t];
    float4 v4 = cb4[1024 + t];
    float4 vv[5] = {v0, v1, v2, v3, v4};
    #pragma unroll
    for (int i = 0; i < 5; ++i) {
        int f = i * 256 + t;
        int nl = f / 20;                   // 80 % 4 == 0: one row per float4
        float thr = xh[nl];
        float x0 = vv[i].x, x1 = vv[i].y, x2 = vv[i].z, x3 = vv[i].w;
        float mx = fmaxf(fmaxf(x0, x1), fmaxf(x2, x3));
        if (mx >= thr) {
            float sb = sbv[nl];
            float xs[4] = {x0, x1, x2, x3};
            #pragma unroll
            for (int j = 0; j < 4; ++j) {
                if (xs[j] >= thr) {
                    float s = sb * __builtin_amdgcn_rcpf(1.f + __expf(-xs[j]));
                    int bin = (int)(__float_as_uint(s) >> 17) - BINBASE_;
                    if (bin >= NB_) bin = NB_ - 1;
                    if (bin >= 0) atomicAdd(&lh[bin], 1u);
                }
            }
        }
    }
    __syncthreads();
    if (t < NB_) { unsigned c = lh[t]; if (c) atomicAdd(&hist[b * NB_ + t], c); }
}

// --- cutoff key per batch (1-bin safety for approx binning) ---------------
__global__ void k_findL(const unsigned* __restrict__ hist, unsigned* __restrict__ L) {
    __shared__ unsigned h[NB_];
    const int b = blockIdx.x;
    h[threadIdx.x] = hist[b * NB_ + threadIdx.x];   // blockDim = 128
    __syncthreads();
    if (threadIdx.x == 0) {
        unsigned cum = 0, l = 0x3E000000u;          // fallback: 0.125
        for (int bin = NB_ - 1; bin >= 0; --bin) {
            cum += h[bin];
            if (cum >= TOPN_) {
                int safe = bin - 1; if (safe < 0) safe = 0;
                l = ((unsigned)(BINBASE_ + safe)) << 17;
                break;
            }
        }
        L[b] = l;
    }
}

// ---------------------------------------------------------------------------
// Pass 2: collect (key, idx) with exact key >= L[b]. Same 5-load structure.
// Survivor path is bitwise-identical to the reference score formula.
// ---------------------------------------------------------------------------
__global__ __launch_bounds__(256) void k_collect(const float* __restrict__ cls,
                                                 const float* __restrict__ ctr,
                                                 const unsigned* __restrict__ L,
                                                 unsigned* __restrict__ cnt,
                                                 unsigned long long* __restrict__ cand) {
    __shared__ float xh[64];
    __shared__ float sbv[64];
    const int b = blockIdx.y, bx = blockIdx.x, t = threadIdx.x;
    const unsigned Lb = L[b];
    const float Lf = __uint_as_float(Lb);
    if (t < 64) {
        float sc = sigm(ctr[b * N_ + bx * 64 + t]);
        sbv[t] = sc;
        float q = Lf / sc;
        xh[t] = (q < 1.f) ? (logf(q / (1.f - q)) - 1e-3f) : 3.0e38f;
    }
    __syncthreads();
    const float4* cb4 = (const float4*)(cls + (size_t)b * NC_ + (size_t)bx * 5120);
    float4 v0 = cb4[t];
    float4 v1 = cb4[256 + t];
    float4 v2 = cb4[512 + t];
    float4 v3 = cb4[768 + t];
    float4 v4 = cb4[1024 + t];
    float4 vv[5] = {v0, v1, v2, v3, v4};
    const unsigned ebase = (unsigned)bx * 5120u;
    #pragma unroll
    for (int i = 0; i < 5; ++i) {
        int f = i * 256 + t;
        int nl = f / 20;
        float thr = xh[nl];
        float x0 = vv[i].x, x1 = vv[i].y, x2 = vv[i].z, x3 = vv[i].w;
        float mx = fmaxf(fmaxf(x0, x1), fmaxf(x2, x3));
        if (mx >= thr) {
            float sb = sbv[nl];
            float xs[4] = {x0, x1, x2, x3};
            #pragma unroll
            for (int j = 0; j < 4; ++j) {
                if (xs[j] >= thr) {
                    float s = sigm(xs[j]);              // exact, matches reference
                    if (s > 0.05f) {                    // conf mask (exact)
                        unsigned key = __float_as_uint(s * sb);
                        if (key >= Lb) {
                            unsigned pos = atomicAdd(&cnt[b], 1u);
                            if (pos < CAP_) {
                                unsigned e = ebase + 4u * (unsigned)f + (unsigned)j;
                                cand[(size_t)b * CAP_ + pos] =
                                    ((unsigned long long)key << 32) |
                                    (unsigned long long)(0xFFFFFFFFu - e);
                            }
                        }
                    }
                }
            }
        }
    }
}

// ---------------------------------------------------------------------------
// Fused: bitonic sort (desc) in LDS + decode top-1024 + validmask via ballot.
// ---------------------------------------------------------------------------
__global__ __launch_bounds__(1024) void k_sortdec(
        const unsigned long long* __restrict__ cand, const unsigned* __restrict__ cnt,
        const float* __restrict__ boxes, const float* __restrict__ locs,
        const int* __restrict__ ph, const int* __restrict__ pw,
        float4* __restrict__ det, float4* __restrict__ deto,
        float* __restrict__ score, int* __restrict__ lab,
        unsigned long long* __restrict__ validmask) {
    __shared__ unsigned long long a[CAP_];
    const int b = blockIdx.x, t = threadIdx.x;
    unsigned c = cnt[b]; if (c > CAP_) c = CAP_;
    int M = 1024; while (M < (int)c) M <<= 1;       // block-uniform
    const unsigned long long* g = cand + (size_t)b * CAP_;
    for (int i = t; i < M; i += 1024) a[i] = (i < (int)c) ? g[i] : 0ull;
    __syncthreads();
    for (int k = 2; k <= M; k <<= 1) {
        for (int j = k >> 1; j > 0; j >>= 1) {
            for (int i = t; i < M; i += 1024) {
                int ixj = i ^ j;
                if (ixj > i) {
                    unsigned long long x = a[i], y = a[ixj];
                    bool desc = ((i & k) == 0);
                    if (desc ? (x < y) : (x > y)) { a[i] = y; a[ixj] = x; }
                }
            }
            __syncthreads();
        }
    }
    // decode rank t
    unsigned long long comp = a[t];
    unsigned key = (unsigned)(comp >> 32);
    float4 d = {0.f, 0.f, 0.f, 0.f}, doff = {0.f, 0.f, 0.f, 0.f};
    float sc = 0.f; int lb = 0;
    if (key) {
        unsigned idx = 0xFFFFFFFFu - (unsigned)comp;
        unsigned loc = idx / (unsigned)C_;
        unsigned cc = idx - loc * (unsigned)C_;
        lb = (int)cc + 1;
        float4 pb = ((const float4*)boxes)[(size_t)b * N_ + loc];
        float lx = locs[2 * loc], ly = locs[2 * loc + 1];
        float Wm1 = (float)(pw[0] - 1), Hm1 = (float)(ph[0] - 1);
        d.x = fminf(fmaxf(lx - pb.x, 0.f), Wm1);
        d.y = fminf(fmaxf(ly - pb.y, 0.f), Hm1);
        d.z = fminf(fmaxf(lx + pb.z, 0.f), Wm1);
        d.w = fminf(fmaxf(ly + pb.w, 0.f), Hm1);
        sc = __uint_as_float(key);
        float off = (float)lb * 4096.0f;
        doff.x = d.x + off; doff.y = d.y + off; doff.z = d.z + off; doff.w = d.w + off;
    }
    unsigned long long ball = __ballot(key != 0u);
    if ((t & 63) == 0) validmask[b * 16 + (t >> 6)] = ball;
    det[b * 1024 + t] = d;
    deto[b * 1024 + t] = doff;
    score[b * 1024 + t] = sc;
    lab[b * 1024 + t] = lb;
}

// --- suppression bitmask: sup[i][w] bit jj = (iou(i, w*64+jj) > .6 && j > i)
__global__ void k_sup(const float4* __restrict__ deto, unsigned long long* __restrict__ sup) {
    __shared__ float4 bx[1024];
    const int b = blockIdx.y;
    for (int i = threadIdx.x; i < 1024; i += blockDim.x) bx[i] = deto[b * 1024 + i];
    __syncthreads();
    int t = threadIdx.x;               // 256 threads: 16 rows x 16 words
    int i = blockIdx.x * 16 + (t >> 4);
    int w = t & 15;
    if (i < TOPN_) {
        float4 A = bx[i];
        float aA = fmaxf(A.z - A.x, 0.f) * fmaxf(A.w - A.y, 0.f);
        unsigned long long m = 0;
        int j0 = w * 64;
        #pragma unroll 4
        for (int jj = 0; jj < 64; ++jj) {
            int j = j0 + jj;
            if (j > i && j < TOPN_) {
                float4 Bv = bx[j];
                float aB = fmaxf(Bv.z - Bv.x, 0.f) * fmaxf(Bv.w - Bv.y, 0.f);
                float ix1 = fmaxf(A.x, Bv.x), iy1 = fmaxf(A.y, Bv.y);
                float ix2 = fminf(A.z, Bv.z), iy2 = fminf(A.w, Bv.w);
                float inter = fmaxf(ix2 - ix1, 0.f) * fmaxf(iy2 - iy1, 0.f);
                float iou = inter / (aA + aB - inter + 1e-9f);
                if (iou > 0.6f) m |= (1ull << jj);
            }
        }
        sup[((size_t)b * 1024 + i) * 16 + w] = m;
    }
}

// ---------------------------------------------------------------------------
// Fused: sequential greedy NMS scan (wave 0) + masked output write (all).
// ---------------------------------------------------------------------------
__global__ __launch_bounds__(1024) void k_nmsout(
        const unsigned long long* __restrict__ sup,
        const unsigned long long* __restrict__ validmask,
        const float4* __restrict__ det, const float* __restrict__ score,
        const int* __restrict__ lab, float* __restrict__ out) {
    __shared__ unsigned long long keepw[16];
    const int b = blockIdx.x, t = threadIdx.x;
    if (t < 64) {
        unsigned long long vw = validmask[b * 16 + (t & 15)];
        unsigned long long remv = 0;
        const unsigned long long* S = sup + (size_t)b * 1024 * 16;
        for (int i = 0; i < TOPN_; ++i) {
            unsigned long long row = S[(size_t)i * 16 + (t & 15)];
            int wsrc = i >> 6;
            unsigned long long vv = __shfl(vw, wsrc);
            unsigned long long rr = __shfl(remv, wsrc);
            bool keep = (((vv >> (i & 63)) & 1ull) != 0) && (((rr >> (i & 63)) & 1ull) == 0);
            remv |= keep ? row : 0ull;     // row has j>i baked in
        }
        if (t < 16) keepw[t] = vw & ~remv;
    }
    __syncthreads();
    if (t < TOPN_) {
        bool kp = ((keepw[t >> 6] >> (t & 63)) & 1ull) != 0;
        float4 d = det[b * 1024 + t];
        ((float4*)out)[(size_t)b * TOPN_ + t] = kp ? d : make_float4(0.f, 0.f, 0.f, 0.f);
        out[B_ * TOPN_ * 4 + b * TOPN_ + t] = kp ? score[b * 1024 + t] : 0.f;
        out[B_ * TOPN_ * 5 + b * TOPN_ + t] = kp ? (float)lab[b * 1024 + t] : 0.f;
    }
}

extern "C" void kernel_launch(void* const* d_in, const int* in_sizes, int n_in,
                              void* d_out, int out_size, void* d_ws, size_t ws_size,
                              hipStream_t stream) {
    (void)in_sizes; (void)n_in; (void)out_size; (void)ws_size;
    const float* locations = (const float*)d_in[0];   // (16384, 2)
    const float* pred_cls  = (const float*)d_in[1];   // (16, 128, 128, 80)
    const float* pred_box  = (const float*)d_in[2];   // (16, 128, 128, 4)
    const float* pred_ctr  = (const float*)d_in[3];   // (16, 128, 128)
    const int*   ph        = (const int*)d_in[4];     // 1024
    const int*   pw        = (const int*)d_in[5];     // 1024
    float* out = (float*)d_out;

    char* w = (char*)d_ws;
    unsigned* hist               = (unsigned*)(w + OFF_HIST);
    unsigned* cnt                = (unsigned*)(w + OFF_CNT);
    unsigned* L                  = (unsigned*)(w + OFF_L);
    unsigned long long* validmsk = (unsigned long long*)(w + OFF_VALID);
    unsigned long long* cand     = (unsigned long long*)(w + OFF_CAND);
    float4* det                  = (float4*)(w + OFF_DET);
    float4* deto                 = (float4*)(w + OFF_DETO);
    float* score                 = (float*)(w + OFF_SCORE);
    int* lab                     = (int*)(w + OFF_LAB);
    unsigned long long* sup      = (unsigned long long*)(w + OFF_SUP);

    hipMemsetAsync(w, 0, ZERO_BYTES, stream);   // hist + cnt only

    k_hist<<<dim3(256, B_), 256, 0, stream>>>(pred_cls, pred_ctr, hist);
    k_findL<<<B_, NB_, 0, stream>>>(hist, L);
    k_collect<<<dim3(256, B_), 256, 0, stream>>>(pred_cls, pred_ctr, L, cnt, cand);
    k_sortdec<<<B_, 1024, 0, stream>>>(cand, cnt, pred_box, locations, ph, pw,
                                       det, deto, score, lab, validmsk);
    k_sup<<<dim3(63, B_), 256, 0, stream>>>(deto, sup);
    k_nmsout<<<B_, 1024, 0, stream>>>(sup, validmsk, det, score, lab, out);
}

// Round 4
// 319.000 us; speedup vs baseline: 1.5781x; 1.5781x over previous
//
#include <hip/hip_runtime.h>

// Problem constants (fixed by setup_inputs)
#define B_    16
#define N_    16384
#define C_    80
#define NC_   (N_ * C_)      // 1310720 per batch
#define TOPN_ 1000
#define CAP2_ 16384          // collected candidates per batch
#define T0_   0.70f
#define T0KEY_ 0x3F333333u   // bits(0.70f)
#define RKEY_  0x3E800000u   // bits(0.25f) rescue threshold
#define BASE12_ 0x3E800u     // RKEY_ >> 12
#define NBIN_  4096          // 4096 bins of 2^12 ULP cover [0.25, 1.0)

// Workspace layout (bytes, 256-aligned). Zero region = [0, ZERO_BYTES)
#define OFF_CNT    0u        // 16 * 64 B padded counters: [b*16+0]=count, [+1]=ovf
#define ZERO_BYTES 1024u
#define OFF_CAND   1024u     // 16*16384*8 = 2097152
#define OFF_DET    2098176u  // 16*1024*16 = 262144 (float4)
#define OFF_DETO   2360320u  // 262144
#define OFF_SCORE  2622464u  // 65536
#define OFF_LAB    2688000u  // 65536
#define OFF_VALID  2753536u  // 2048
#define OFF_SUP    2755584u  // 16*1024*16*8 = 2097152
// total ~4.6 MB

__device__ __forceinline__ float sigm(float x) { return 1.0f / (1.0f + expf(-x)); }

// ---------------------------------------------------------------------------
// Single streaming pass. Grid 2048 x 256: block = (b = blk>>7, k = blk&127),
// owns rows [k*128, +128) = 2560 float4 = 40 KB of cls, contiguous.
// Survivors (exact score >= T0) staged in LDS; ONE global atomic per block
// to a 64B-padded counter. Explicit 2-deep x 2-wide register prefetch.
// ---------------------------------------------------------------------------
__global__ __launch_bounds__(256) void k_pass1(const float* __restrict__ cls,
                                               const float* __restrict__ ctr,
                                               unsigned* __restrict__ cntp,
                                               unsigned long long* __restrict__ cand) {
    __shared__ float xh[128];    // conservative raw-logit threshold per row
    __shared__ float sbv[128];   // exact sigmoid(centerness) per row
    __shared__ unsigned long long stage[1024];
    __shared__ unsigned lcnt, gbase, lcw;
    const int blk = blockIdx.x, t = threadIdx.x;
    const int b = blk >> 7, k = blk & 127;
    if (t == 0) lcnt = 0;
    if (t < 128) {
        float sc = sigm(ctr[b * N_ + k * 128 + t]);
        sbv[t] = sc;
        float q = T0_ / sc;
        xh[t] = (q < 1.f) ? (logf(q / (1.f - q)) - 1e-3f) : 3.0e38f;
    }
    __syncthreads();
    const float4* p = (const float4*)(cls + (size_t)b * NC_ + (size_t)k * 10240);
    float4 a0 = p[t], a1 = p[256 + t];
    for (int it = 0; it < 5; ++it) {
        float4 n0 = {0,0,0,0}, n1 = {0,0,0,0};
        if (it < 4) { n0 = p[(it + 1) * 512 + t]; n1 = p[(it + 1) * 512 + 256 + t]; }
        #pragma unroll
        for (int h = 0; h < 2; ++h) {
            float4 v = h ? a1 : a0;
            int f = it * 512 + h * 256 + t;        // float4 index within chunk [0,2560)
            int nl = f / 20;                        // row (80 floats = 20 float4 per row)
            float thr = xh[nl];
            float mx = fmaxf(fmaxf(v.x, v.y), fmaxf(v.z, v.w));
            if (mx >= thr) {
                float sb = sbv[nl];
                float xs[4] = {v.x, v.y, v.z, v.w};
                #pragma unroll
                for (int j = 0; j < 4; ++j) {
                    if (xs[j] >= thr) {
                        float s = sigm(xs[j]);               // exact, matches reference
                        unsigned key = __float_as_uint(s * sb);
                        if (key >= T0KEY_) {                 // score >= 0.70 (implies conf mask)
                            unsigned pos = atomicAdd(&lcnt, 1u);
                            if (pos < 1024u) {
                                unsigned e = (unsigned)(k * 2560 + f) * 4u + (unsigned)j;
                                stage[pos] = ((unsigned long long)key << 32) |
                                             (unsigned long long)(0xFFFFFFFFu - e);
                            }
                        }
                    }
                }
            }
        }
        a0 = n0; a1 = n1;
    }
    __syncthreads();
    if (t == 0) {
        unsigned lc = lcnt; if (lc > 1024u) { lc = 1024u; cntp[b * 16 + 1] = 1u; }
        gbase = atomicAdd(&cntp[b * 16], lc);
        lcw = lc;
    }
    __syncthreads();
    for (unsigned i = t; i < lcw; i += 256) {
        unsigned gp = gbase + i;
        if (gp < CAP2_) cand[(size_t)b * CAP2_ + gp] = stage[i];
    }
}

// ---------------------------------------------------------------------------
// Rescue (always launched; early-exits when cnt>=1000). Appends survivors with
// key in [0.25, 0.70) for under-filled batches. Same chunking as k_pass1.
// ---------------------------------------------------------------------------
__global__ __launch_bounds__(256) void k_rescue(const float* __restrict__ cls,
                                                const float* __restrict__ ctr,
                                                unsigned* __restrict__ cntp,
                                                unsigned long long* __restrict__ cand) {
    const int blk = blockIdx.x, t = threadIdx.x;
    const int b = blk >> 7, k = blk & 127;
    if (cntp[b * 16] >= (unsigned)TOPN_) return;     // common case: done
    __shared__ float xh[128];
    __shared__ float sbv[128];
    __shared__ unsigned long long stage[1024];
    __shared__ unsigned lcnt, gbase, lcw;
    if (t == 0) lcnt = 0;
    if (t < 128) {
        float sc = sigm(ctr[b * N_ + k * 128 + t]);
        sbv[t] = sc;
        float q = 0.25f / sc;
        xh[t] = (q < 1.f) ? (logf(q / (1.f - q)) - 1e-3f) : 3.0e38f;
    }
    __syncthreads();
    const float4* p = (const float4*)(cls + (size_t)b * NC_ + (size_t)k * 10240);
    for (int f = t; f < 2560; f += 256) {
        float4 v = p[f];
        int nl = f / 20;
        float thr = xh[nl];
        float mx = fmaxf(fmaxf(v.x, v.y), fmaxf(v.z, v.w));
        if (mx >= thr) {
            float sb = sbv[nl];
            float xs[4] = {v.x, v.y, v.z, v.w};
            #pragma unroll
            for (int j = 0; j < 4; ++j) {
                if (xs[j] >= thr) {
                    float s = sigm(xs[j]);
                    if (s > 0.05f) {
                        unsigned key = __float_as_uint(s * sb);
                        if (key >= RKEY_ && key < T0KEY_) {   // not already collected
                            unsigned pos = atomicAdd(&lcnt, 1u);
                            if (pos < 1024u) {
                                unsigned e = (unsigned)(k * 2560 + f) * 4u + (unsigned)j;
                                stage[pos] = ((unsigned long long)key << 32) |
                                             (unsigned long long)(0xFFFFFFFFu - e);
                            }
                        }
                    }
                }
            }
        }
    }
    __syncthreads();
    if (t == 0) {
        unsigned lc = lcnt; if (lc > 1024u) lc = 1024u;
        gbase = atomicAdd(&cntp[b * 16], lc);
        lcw = lc;
    }
    __syncthreads();
    for (unsigned i = t; i < lcw; i += 256) {
        unsigned gp = gbase + i;
        if (gp < CAP2_) cand[(size_t)b * CAP2_ + gp] = stage[i];
    }
}

// ---------------------------------------------------------------------------
// Per-batch select: exact-key histogram -> cutoff L -> compact -> bitonic-2048
// -> decode top-1024 + validmask. One block (1024 thr) per batch.
// ---------------------------------------------------------------------------
__global__ __launch_bounds__(1024) void k_select(
        const unsigned long long* __restrict__ cand, const unsigned* __restrict__ cntp,
        const float* __restrict__ boxes, const float* __restrict__ locs,
        const int* __restrict__ ph, const int* __restrict__ pw,
        float4* __restrict__ det, float4* __restrict__ deto,
        float* __restrict__ score, int* __restrict__ lab,
        unsigned long long* __restrict__ validmask) {
    __shared__ unsigned hbin[NBIN_];
    __shared__ unsigned long long srt[2048];
    __shared__ unsigned scnt, Lsh;
    const int b = blockIdx.x, t = threadIdx.x;
    unsigned c = cntp[b * 16]; if (c > CAP2_) c = CAP2_;
    for (int i = t; i < NBIN_; i += 1024) hbin[i] = 0;
    srt[t] = 0ull; srt[t + 1024] = 0ull;
    if (t == 0) scnt = 0;
    __syncthreads();
    const unsigned long long* g = cand + (size_t)b * CAP2_;
    for (unsigned i = t; i < c; i += 1024) {
        unsigned key = (unsigned)(g[i] >> 32);
        int bin = (int)(key >> 12) - (int)BASE12_;
        if (bin < 0) bin = 0; if (bin >= NBIN_) bin = NBIN_ - 1;
        atomicAdd(&hbin[bin], 1u);
    }
    __syncthreads();
    if (t == 0) {
        unsigned cum = 0; unsigned l = RKEY_;
        for (int bin = NBIN_ - 1; bin >= 0; --bin) {
            cum += hbin[bin];
            if (cum >= (unsigned)TOPN_) { l = ((unsigned)BASE12_ + (unsigned)bin) << 12; break; }
        }
        Lsh = l;
    }
    __syncthreads();
    unsigned L = Lsh;
    for (unsigned i = t; i < c; i += 1024) {
        unsigned long long comp = g[i];
        if ((unsigned)(comp >> 32) >= L) {
            unsigned pos = atomicAdd(&scnt, 1u);
            if (pos < 2048u) srt[pos] = comp;
        }
    }
    __syncthreads();
    // bitonic sort 2048 descending (composite: key desc, idx asc)
    for (int k = 2; k <= 2048; k <<= 1) {
        for (int j = k >> 1; j > 0; j >>= 1) {
            for (int i = t; i < 2048; i += 1024) {
                int ixj = i ^ j;
                if (ixj > i) {
                    unsigned long long x = srt[i], y = srt[ixj];
                    bool desc = ((i & k) == 0);
                    if (desc ? (x < y) : (x > y)) { srt[i] = y; srt[ixj] = x; }
                }
            }
            __syncthreads();
        }
    }
    // decode rank t
    unsigned long long comp = srt[t];
    unsigned key = (unsigned)(comp >> 32);
    float4 d = {0.f, 0.f, 0.f, 0.f}, doff = {0.f, 0.f, 0.f, 0.f};
    float sc = 0.f; int lb = 0;
    if (key) {
        unsigned idx = 0xFFFFFFFFu - (unsigned)comp;
        unsigned loc = idx / (unsigned)C_;
        unsigned cc = idx - loc * (unsigned)C_;
        lb = (int)cc + 1;
        float4 pb = ((const float4*)boxes)[(size_t)b * N_ + loc];
        float lx = locs[2 * loc], ly = locs[2 * loc + 1];
        float Wm1 = (float)(pw[0] - 1), Hm1 = (float)(ph[0] - 1);
        d.x = fminf(fmaxf(lx - pb.x, 0.f), Wm1);
        d.y = fminf(fmaxf(ly - pb.y, 0.f), Hm1);
        d.z = fminf(fmaxf(lx + pb.z, 0.f), Wm1);
        d.w = fminf(fmaxf(ly + pb.w, 0.f), Hm1);
        sc = __uint_as_float(key);
        float off = (float)lb * 4096.0f;
        doff.x = d.x + off; doff.y = d.y + off; doff.z = d.z + off; doff.w = d.w + off;
    }
    unsigned long long ball = __ballot(key != 0u);
    if ((t & 63) == 0) validmask[b * 16 + (t >> 6)] = ball;
    det[b * 1024 + t] = d;
    deto[b * 1024 + t] = doff;
    score[b * 1024 + t] = sc;
    lab[b * 1024 + t] = lb;
}

// --- suppression bitmask: sup[i][w] bit jj = (iou(i, w*64+jj) > .6 && j > i)
__global__ void k_sup(const float4* __restrict__ deto, unsigned long long* __restrict__ sup) {
    __shared__ float4 bx[1024];
    const int b = blockIdx.y;
    for (int i = threadIdx.x; i < 1024; i += blockDim.x) bx[i] = deto[b * 1024 + i];
    __syncthreads();
    int t = threadIdx.x;               // 256 threads: 16 rows x 16 words
    int i = blockIdx.x * 16 + (t >> 4);
    int w = t & 15;
    if (i < TOPN_) {
        float4 A = bx[i];
        float aA = fmaxf(A.z - A.x, 0.f) * fmaxf(A.w - A.y, 0.f);
        unsigned long long m = 0;
        int j0 = w * 64;
        #pragma unroll 4
        for (int jj = 0; jj < 64; ++jj) {
            int j = j0 + jj;
            if (j > i && j < TOPN_) {
                float4 Bv = bx[j];
                float aB = fmaxf(Bv.z - Bv.x, 0.f) * fmaxf(Bv.w - Bv.y, 0.f);
                float ix1 = fmaxf(A.x, Bv.x), iy1 = fmaxf(A.y, Bv.y);
                float ix2 = fminf(A.z, Bv.z), iy2 = fminf(A.w, Bv.w);
                float inter = fmaxf(ix2 - ix1, 0.f) * fmaxf(iy2 - iy1, 0.f);
                float iou = inter / (aA + aB - inter + 1e-9f);
                if (iou > 0.6f) m |= (1ull << jj);
            }
        }
        sup[((size_t)b * 1024 + i) * 16 + w] = m;
    }
}

// ---------------------------------------------------------------------------
// Fused NMS scan + output. Wave 0 scans; other waves double-buffer sup tiles
// (128 rows x 16 words = 16 KB) into LDS to hide latency.
// ---------------------------------------------------------------------------
__global__ __launch_bounds__(1024) void k_nmsout(
        const unsigned long long* __restrict__ sup,
        const unsigned long long* __restrict__ validmask,
        const float4* __restrict__ det, const float* __restrict__ score,
        const int* __restrict__ lab, float* __restrict__ out) {
    __shared__ unsigned long long tile[2][2048];
    __shared__ unsigned long long keepw[16];
    const int b = blockIdx.x, t = threadIdx.x;
    const unsigned long long* S = sup + (size_t)b * 16384;
    tile[0][t] = S[t]; tile[0][t + 1024] = S[t + 1024];
    __syncthreads();
    unsigned long long vw = 0, remv = 0;
    if (t < 64) vw = validmask[b * 16 + (t & 15)];
    for (int blk = 0; blk < 8; ++blk) {
        if (blk < 7 && t >= 64) {
            int base = (blk + 1) * 2048;
            for (int i = t - 64; i < 2048; i += 960) tile[(blk + 1) & 1][i] = S[base + i];
        }
        if (t < 64) {
            int lim = TOPN_ - blk * 128; if (lim > 128) lim = 128;
            for (int ii = 0; ii < lim; ++ii) {
                int i = blk * 128 + ii;
                unsigned long long row = tile[blk & 1][ii * 16 + (t & 15)];
                int wsrc = i >> 6;
                unsigned long long vv = __shfl(vw, wsrc);
                unsigned long long rr = __shfl(remv, wsrc);
                bool keep = (((vv >> (i & 63)) & 1ull) != 0) && (((rr >> (i & 63)) & 1ull) == 0);
                remv |= keep ? row : 0ull;
            }
        }
        __syncthreads();
    }
    if (t < 16) keepw[t] = vw & ~remv;
    __syncthreads();
    if (t < TOPN_) {
        bool kp = ((keepw[t >> 6] >> (t & 63)) & 1ull) != 0;
        float4 d = det[b * 1024 + t];
        ((float4*)out)[(size_t)b * TOPN_ + t] = kp ? d : make_float4(0.f, 0.f, 0.f, 0.f);
        out[B_ * TOPN_ * 4 + b * TOPN_ + t] = kp ? score[b * 1024 + t] : 0.f;
        out[B_ * TOPN_ * 5 + b * TOPN_ + t] = kp ? (float)lab[b * 1024 + t] : 0.f;
    }
}

extern "C" void kernel_launch(void* const* d_in, const int* in_sizes, int n_in,
                              void* d_out, int out_size, void* d_ws, size_t ws_size,
                              hipStream_t stream) {
    (void)in_sizes; (void)n_in; (void)out_size; (void)ws_size;
    const float* locations = (const float*)d_in[0];   // (16384, 2)
    const float* pred_cls  = (const float*)d_in[1];   // (16, 128, 128, 80)
    const float* pred_box  = (const float*)d_in[2];   // (16, 128, 128, 4)
    const float* pred_ctr  = (const float*)d_in[3];   // (16, 128, 128)
    const int*   ph        = (const int*)d_in[4];     // 1024
    const int*   pw        = (const int*)d_in[5];     // 1024
    float* out = (float*)d_out;

    char* w = (char*)d_ws;
    unsigned* cntp               = (unsigned*)(w + OFF_CNT);
    unsigned long long* cand     = (unsigned long long*)(w + OFF_CAND);
    float4* det                  = (float4*)(w + OFF_DET);
    float4* deto                 = (float4*)(w + OFF_DETO);
    float* score                 = (float*)(w + OFF_SCORE);
    int* lab                     = (int*)(w + OFF_LAB);
    unsigned long long* validmsk = (unsigned long long*)(w + OFF_VALID);
    unsigned long long* sup      = (unsigned long long*)(w + OFF_SUP);

    hipMemsetAsync(w, 0, ZERO_BYTES, stream);   // padded counters only

    k_pass1<<<2048, 256, 0, stream>>>(pred_cls, pred_ctr, cntp, cand);
    k_rescue<<<2048, 256, 0, stream>>>(pred_cls, pred_ctr, cntp, cand);
    k_select<<<B_, 1024, 0, stream>>>(cand, cntp, pred_box, locations, ph, pw,
                                      det, deto, score, lab, validmsk);
    k_sup<<<dim3(63, B_), 256, 0, stream>>>(deto, sup);
    k_nmsout<<<B_, 1024, 0, stream>>>(sup, validmsk, det, score, lab, out);
}

// Round 5
// 253.703 us; speedup vs baseline: 1.9843x; 1.2574x over previous
//
#include <hip/hip_runtime.h>

// Problem constants (fixed by setup_inputs)
#define B_    16
#define N_    16384
#define C_    80
#define NC_   (N_ * C_)      // 1310720 per batch
#define TOPN_ 1000
#define CAP2_ 16384          // collected candidates per batch
#define T0_   0.70f
#define T0KEY_ 0x3F333333u   // bits(0.70f)
#define RKEY_  0x3E800000u   // bits(0.25f) rescue threshold
#define BASE12_ 0x3E800u     // RKEY_ >> 12
#define NBIN_  4096          // 4096 bins of 2^12 ULP cover [0.25, 1.0)

// Workspace layout (bytes, 256-aligned). Zero region = [0, ZERO_BYTES)
#define OFF_CNT    0u        // 16 * 64 B padded counters: [b*16+0]=count, [+1]=ovf
#define ZERO_BYTES 1024u
#define OFF_CAND   1024u     // 16*16384*8 = 2097152
#define OFF_DET    2098176u  // 16*1024*16 = 262144 (float4)
#define OFF_DETO   2360320u  // 262144
#define OFF_SCORE  2622464u  // 65536
#define OFF_LAB    2688000u  // 65536
#define OFF_VALID  2753536u  // 2048
#define OFF_COL    2755584u  // colsup: 16*1024*16*8 = 2097152
// total ~4.6 MB

__device__ __forceinline__ float sigm(float x) { return 1.0f / (1.0f + expf(-x)); }

// ---------------------------------------------------------------------------
// Single streaming pass. Grid 2048 x 256: block = (b = blk>>7, k = blk&127),
// owns rows [k*128, +128) = 2560 float4 = 40 KB of cls, contiguous.
// Survivors (exact score >= T0) staged in LDS; ONE global atomic per block
// to a 64B-padded counter.
// ---------------------------------------------------------------------------
__global__ __launch_bounds__(256) void k_pass1(const float* __restrict__ cls,
                                               const float* __restrict__ ctr,
                                               unsigned* __restrict__ cntp,
                                               unsigned long long* __restrict__ cand) {
    __shared__ float xh[128];    // conservative raw-logit threshold per row
    __shared__ float sbv[128];   // exact sigmoid(centerness) per row
    __shared__ unsigned long long stage[1024];
    __shared__ unsigned lcnt, gbase, lcw;
    const int blk = blockIdx.x, t = threadIdx.x;
    const int b = blk >> 7, k = blk & 127;
    if (t == 0) lcnt = 0;
    if (t < 128) {
        float sc = sigm(ctr[b * N_ + k * 128 + t]);
        sbv[t] = sc;
        float q = T0_ / sc;
        xh[t] = (q < 1.f) ? (logf(q / (1.f - q)) - 1e-3f) : 3.0e38f;
    }
    __syncthreads();
    const float4* p = (const float4*)(cls + (size_t)b * NC_ + (size_t)k * 10240);
    float4 a0 = p[t], a1 = p[256 + t];
    for (int it = 0; it < 5; ++it) {
        float4 n0 = {0,0,0,0}, n1 = {0,0,0,0};
        if (it < 4) { n0 = p[(it + 1) * 512 + t]; n1 = p[(it + 1) * 512 + 256 + t]; }
        #pragma unroll
        for (int h = 0; h < 2; ++h) {
            float4 v = h ? a1 : a0;
            int f = it * 512 + h * 256 + t;        // float4 index within chunk [0,2560)
            int nl = f / 20;                        // row (80 floats = 20 float4 per row)
            float thr = xh[nl];
            float mx = fmaxf(fmaxf(v.x, v.y), fmaxf(v.z, v.w));
            if (mx >= thr) {
                float sb = sbv[nl];
                float xs[4] = {v.x, v.y, v.z, v.w};
                #pragma unroll
                for (int j = 0; j < 4; ++j) {
                    if (xs[j] >= thr) {
                        float s = sigm(xs[j]);               // exact, matches reference
                        unsigned key = __float_as_uint(s * sb);
                        if (key >= T0KEY_) {                 // score >= 0.70 (implies conf mask)
                            unsigned pos = atomicAdd(&lcnt, 1u);
                            if (pos < 1024u) {
                                unsigned e = (unsigned)(k * 2560 + f) * 4u + (unsigned)j;
                                stage[pos] = ((unsigned long long)key << 32) |
                                             (unsigned long long)(0xFFFFFFFFu - e);
                            }
                        }
                    }
                }
            }
        }
        a0 = n0; a1 = n1;
    }
    __syncthreads();
    if (t == 0) {
        unsigned lc = lcnt; if (lc > 1024u) { lc = 1024u; cntp[b * 16 + 1] = 1u; }
        gbase = atomicAdd(&cntp[b * 16], lc);
        lcw = lc;
    }
    __syncthreads();
    for (unsigned i = t; i < lcw; i += 256) {
        unsigned gp = gbase + i;
        if (gp < CAP2_) cand[(size_t)b * CAP2_ + gp] = stage[i];
    }
}

// ---------------------------------------------------------------------------
// Rescue (always launched; early-exits when cnt>=1000). Appends survivors with
// key in [0.25, 0.70) for under-filled batches.
// ---------------------------------------------------------------------------
__global__ __launch_bounds__(256) void k_rescue(const float* __restrict__ cls,
                                                const float* __restrict__ ctr,
                                                unsigned* __restrict__ cntp,
                                                unsigned long long* __restrict__ cand) {
    const int blk = blockIdx.x, t = threadIdx.x;
    const int b = blk >> 7, k = blk & 127;
    if (cntp[b * 16] >= (unsigned)TOPN_) return;     // common case: done
    __shared__ float xh[128];
    __shared__ float sbv[128];
    __shared__ unsigned long long stage[1024];
    __shared__ unsigned lcnt, gbase, lcw;
    if (t == 0) lcnt = 0;
    if (t < 128) {
        float sc = sigm(ctr[b * N_ + k * 128 + t]);
        sbv[t] = sc;
        float q = 0.25f / sc;
        xh[t] = (q < 1.f) ? (logf(q / (1.f - q)) - 1e-3f) : 3.0e38f;
    }
    __syncthreads();
    const float4* p = (const float4*)(cls + (size_t)b * NC_ + (size_t)k * 10240);
    for (int f = t; f < 2560; f += 256) {
        float4 v = p[f];
        int nl = f / 20;
        float thr = xh[nl];
        float mx = fmaxf(fmaxf(v.x, v.y), fmaxf(v.z, v.w));
        if (mx >= thr) {
            float sb = sbv[nl];
            float xs[4] = {v.x, v.y, v.z, v.w};
            #pragma unroll
            for (int j = 0; j < 4; ++j) {
                if (xs[j] >= thr) {
                    float s = sigm(xs[j]);
                    if (s > 0.05f) {
                        unsigned key = __float_as_uint(s * sb);
                        if (key >= RKEY_ && key < T0KEY_) {   // not already collected
                            unsigned pos = atomicAdd(&lcnt, 1u);
                            if (pos < 1024u) {
                                unsigned e = (unsigned)(k * 2560 + f) * 4u + (unsigned)j;
                                stage[pos] = ((unsigned long long)key << 32) |
                                             (unsigned long long)(0xFFFFFFFFu - e);
                            }
                        }
                    }
                }
            }
        }
    }
    __syncthreads();
    if (t == 0) {
        unsigned lc = lcnt; if (lc > 1024u) lc = 1024u;
        gbase = atomicAdd(&cntp[b * 16], lc);
        lcw = lc;
    }
    __syncthreads();
    for (unsigned i = t; i < lcw; i += 256) {
        unsigned gp = gbase + i;
        if (gp < CAP2_) cand[(size_t)b * CAP2_ + gp] = stage[i];
    }
}

// ---------------------------------------------------------------------------
// Per-batch select: exact-key histogram -> cutoff L -> compact -> bitonic-2048
// -> decode top-1024 + validmask. One block (1024 thr) per batch.
// ---------------------------------------------------------------------------
__global__ __launch_bounds__(1024) void k_select(
        const unsigned long long* __restrict__ cand, const unsigned* __restrict__ cntp,
        const float* __restrict__ boxes, const float* __restrict__ locs,
        const int* __restrict__ ph, const int* __restrict__ pw,
        float4* __restrict__ det, float4* __restrict__ deto,
        float* __restrict__ score, int* __restrict__ lab,
        unsigned long long* __restrict__ validmask) {
    __shared__ unsigned hbin[NBIN_];
    __shared__ unsigned long long srt[2048];
    __shared__ unsigned scnt, Lsh;
    const int b = blockIdx.x, t = threadIdx.x;
    unsigned c = cntp[b * 16]; if (c > CAP2_) c = CAP2_;
    for (int i = t; i < NBIN_; i += 1024) hbin[i] = 0;
    srt[t] = 0ull; srt[t + 1024] = 0ull;
    if (t == 0) scnt = 0;
    __syncthreads();
    const unsigned long long* g = cand + (size_t)b * CAP2_;
    for (unsigned i = t; i < c; i += 1024) {
        unsigned key = (unsigned)(g[i] >> 32);
        int bin = (int)(key >> 12) - (int)BASE12_;
        if (bin < 0) bin = 0; if (bin >= NBIN_) bin = NBIN_ - 1;
        atomicAdd(&hbin[bin], 1u);
    }
    __syncthreads();
    if (t == 0) {
        unsigned cum = 0; unsigned l = RKEY_;
        for (int bin = NBIN_ - 1; bin >= 0; --bin) {
            cum += hbin[bin];
            if (cum >= (unsigned)TOPN_) { l = ((unsigned)BASE12_ + (unsigned)bin) << 12; break; }
        }
        Lsh = l;
    }
    __syncthreads();
    unsigned L = Lsh;
    for (unsigned i = t; i < c; i += 1024) {
        unsigned long long comp = g[i];
        if ((unsigned)(comp >> 32) >= L) {
            unsigned pos = atomicAdd(&scnt, 1u);
            if (pos < 2048u) srt[pos] = comp;
        }
    }
    __syncthreads();
    // bitonic sort 2048 descending (composite: key desc, idx asc)
    for (int k = 2; k <= 2048; k <<= 1) {
        for (int j = k >> 1; j > 0; j >>= 1) {
            for (int i = t; i < 2048; i += 1024) {
                int ixj = i ^ j;
                if (ixj > i) {
                    unsigned long long x = srt[i], y = srt[ixj];
                    bool desc = ((i & k) == 0);
                    if (desc ? (x < y) : (x > y)) { srt[i] = y; srt[ixj] = x; }
                }
            }
            __syncthreads();
        }
    }
    // decode rank t
    unsigned long long comp = srt[t];
    unsigned key = (unsigned)(comp >> 32);
    float4 d = {0.f, 0.f, 0.f, 0.f}, doff = {0.f, 0.f, 0.f, 0.f};
    float sc = 0.f; int lb = 0;
    if (key) {
        unsigned idx = 0xFFFFFFFFu - (unsigned)comp;
        unsigned loc = idx / (unsigned)C_;
        unsigned cc = idx - loc * (unsigned)C_;
        lb = (int)cc + 1;
        float4 pb = ((const float4*)boxes)[(size_t)b * N_ + loc];
        float lx = locs[2 * loc], ly = locs[2 * loc + 1];
        float Wm1 = (float)(pw[0] - 1), Hm1 = (float)(ph[0] - 1);
        d.x = fminf(fmaxf(lx - pb.x, 0.f), Wm1);
        d.y = fminf(fmaxf(ly - pb.y, 0.f), Hm1);
        d.z = fminf(fmaxf(lx + pb.z, 0.f), Wm1);
        d.w = fminf(fmaxf(ly + pb.w, 0.f), Hm1);
        sc = __uint_as_float(key);
        float off = (float)lb * 4096.0f;
        doff.x = d.x + off; doff.y = d.y + off; doff.z = d.z + off; doff.w = d.w + off;
    }
    unsigned long long ball = __ballot(key != 0u);
    if ((t & 63) == 0) validmask[b * 16 + (t >> 6)] = ball;
    det[b * 1024 + t] = d;
    deto[b * 1024 + t] = doff;
    score[b * 1024 + t] = sc;
    lab[b * 1024 + t] = lb;
}

// ---------------------------------------------------------------------------
// Transposed suppression matrix: colsup[b][i][w] bit jj = box j=w*64+jj
// suppresses box i, i.e. (iou(i,j) > 0.6 && j < i). Only j<i computed.
// Grid (64, B_) x 256: covers all i in [0,1024) so downstream reads no poison.
// ---------------------------------------------------------------------------
__global__ void k_col(const float4* __restrict__ deto, unsigned long long* __restrict__ colsup) {
    __shared__ float4 bx[1024];
    const int b = blockIdx.y;
    for (int i = threadIdx.x; i < 1024; i += blockDim.x) bx[i] = deto[b * 1024 + i];
    __syncthreads();
    int t = threadIdx.x;               // 256 threads: 16 rows x 16 words
    int i = blockIdx.x * 16 + (t >> 4);
    int w = t & 15;
    int j0 = w * 64;
    unsigned long long m = 0;
    if (i < TOPN_ && j0 < i) {
        float4 A = bx[i];
        float aA = fmaxf(A.z - A.x, 0.f) * fmaxf(A.w - A.y, 0.f);
        int jmax = i - j0; if (jmax > 64) jmax = 64;
        #pragma unroll 4
        for (int jj = 0; jj < jmax; ++jj) {
            float4 Bv = bx[j0 + jj];
            float aB = fmaxf(Bv.z - Bv.x, 0.f) * fmaxf(Bv.w - Bv.y, 0.f);
            float ix1 = fmaxf(A.x, Bv.x), iy1 = fmaxf(A.y, Bv.y);
            float ix2 = fminf(A.z, Bv.z), iy2 = fminf(A.w, Bv.w);
            float inter = fmaxf(ix2 - ix1, 0.f) * fmaxf(iy2 - iy1, 0.f);
            float iou = inter / (aA + aB - inter + 1e-9f);
            if (iou > 0.6f) m |= (1ull << jj);
        }
    }
    colsup[((size_t)b * 1024 + i) * 16 + w] = m;
}

// ---------------------------------------------------------------------------
// NMS via column ballots: 16 groups of 64 processed serially; prior-group
// suppression computed lane-locally from replicated kept words K[w]; intra-
// group lexicographic resolve via iterated-finalization ballot loop.
// Wave 0 resolves; all 1024 threads then write outputs.
// ---------------------------------------------------------------------------
__global__ __launch_bounds__(1024) void k_nmsout(
        const unsigned long long* __restrict__ colsup,
        const unsigned long long* __restrict__ validmask,
        const float4* __restrict__ det, const float* __restrict__ score,
        const int* __restrict__ lab, float* __restrict__ out) {
    __shared__ unsigned long long keepw[16];
    const int b = blockIdx.x, t = threadIdx.x;
    if (t < 64) {
        const int ii = t;
        const unsigned long long* Cb = colsup + (size_t)b * 16384;
        unsigned long long K[16];
        unsigned long long col[16], coln[16];
        #pragma unroll
        for (int w = 0; w < 16; ++w) col[w] = Cb[(size_t)ii * 16 + w];
        unsigned long long vword[16];
        #pragma unroll
        for (int g = 0; g < 16; ++g) vword[g] = validmask[b * 16 + g];
        #pragma unroll
        for (int g = 0; g < 16; ++g) {
            if (g < 15) {       // prefetch next group's columns (hide latency)
                #pragma unroll
                for (int w = 0; w < 16; ++w)
                    coln[w] = Cb[(size_t)((g + 1) * 64 + ii) * 16 + w];
            }
            unsigned long long supprior = 0;
            #pragma unroll
            for (int w = 0; w < 16; ++w) if (w < g) supprior |= K[w] & col[w];
            bool alive = (((vword[g] >> ii) & 1ull) != 0) && (supprior == 0);
            unsigned long long diag = col[g];   // intra-group suppressors (jj < ii)
            unsigned long long undec = __ballot(alive);
            unsigned long long kept = 0;
            while (undec) {
                bool meU = ((undec >> ii) & 1ull) != 0;
                bool supK = (kept & diag) != 0;     // suppressed by finalized-kept
                bool anyU = (undec & diag) != 0;    // potential suppressor undecided
                unsigned long long bkm = __ballot(meU && !supK && !anyU);
                unsigned long long brm = __ballot(meU && supK);
                kept |= bkm;
                undec &= ~(bkm | brm);
            }
            K[g] = kept;
            if (ii == 0) keepw[g] = kept;
            #pragma unroll
            for (int w = 0; w < 16; ++w) col[w] = coln[w];
        }
    }
    __syncthreads();
    if (t < TOPN_) {
        bool kp = ((keepw[t >> 6] >> (t & 63)) & 1ull) != 0;
        float4 d = det[b * 1024 + t];
        ((float4*)out)[(size_t)b * TOPN_ + t] = kp ? d : make_float4(0.f, 0.f, 0.f, 0.f);
        out[B_ * TOPN_ * 4 + b * TOPN_ + t] = kp ? score[b * 1024 + t] : 0.f;
        out[B_ * TOPN_ * 5 + b * TOPN_ + t] = kp ? (float)lab[b * 1024 + t] : 0.f;
    }
}

extern "C" void kernel_launch(void* const* d_in, const int* in_sizes, int n_in,
                              void* d_out, int out_size, void* d_ws, size_t ws_size,
                              hipStream_t stream) {
    (void)in_sizes; (void)n_in; (void)out_size; (void)ws_size;
    const float* locations = (const float*)d_in[0];   // (16384, 2)
    const float* pred_cls  = (const float*)d_in[1];   // (16, 128, 128, 80)
    const float* pred_box  = (const float*)d_in[2];   // (16, 128, 128, 4)
    const float* pred_ctr  = (const float*)d_in[3];   // (16, 128, 128)
    const int*   ph        = (const int*)d_in[4];     // 1024
    const int*   pw        = (const int*)d_in[5];     // 1024
    float* out = (float*)d_out;

    char* w = (char*)d_ws;
    unsigned* cntp               = (unsigned*)(w + OFF_CNT);
    unsigned long long* cand     = (unsigned long long*)(w + OFF_CAND);
    float4* det                  = (float4*)(w + OFF_DET);
    float4* deto                 = (float4*)(w + OFF_DETO);
    float* score                 = (float*)(w + OFF_SCORE);
    int* lab                     = (int*)(w + OFF_LAB);
    unsigned long long* validmsk = (unsigned long long*)(w + OFF_VALID);
    unsigned long long* colsup   = (unsigned long long*)(w + OFF_COL);

    hipMemsetAsync(w, 0, ZERO_BYTES, stream);   // padded counters only

    k_pass1<<<2048, 256, 0, stream>>>(pred_cls, pred_ctr, cntp, cand);
    k_rescue<<<2048, 256, 0, stream>>>(pred_cls, pred_ctr, cntp, cand);
    k_select<<<B_, 1024, 0, stream>>>(cand, cntp, pred_box, locations, ph, pw,
                                      det, deto, score, lab, validmsk);
    k_col<<<dim3(64, B_), 256, 0, stream>>>(deto, colsup);
    k_nmsout<<<B_, 1024, 0, stream>>>(colsup, validmsk, det, score, lab, out);
}

// Round 6
// 219.820 us; speedup vs baseline: 2.2901x; 1.1541x over previous
//
#include <hip/hip_runtime.h>

// Problem constants (fixed by setup_inputs)
#define B_    16
#define N_    16384
#define C_    80
#define NC_   (N_ * C_)      // 1310720 per batch
#define TOPN_ 1000
#define CAP2_ 16384          // collected candidates per batch
#define T0_   0.70f
#define T0KEY_ 0x3F333333u   // bits(0.70f)
#define RKEY_  0x3E800000u   // bits(0.25f) rescue threshold
#define BASE12_ 0x3E800u     // RKEY_ >> 12
#define NBIN_  4096          // 4096 bins of 2^12 ULP cover [0.25, 1.0)

// Workspace layout (bytes, 256-aligned). Zero region = [0, ZERO_BYTES)
#define OFF_CNT    0u        // 16 * 64 B padded counters: [b*16+0]=count, [+1]=ovf
#define ZERO_BYTES 1024u
#define OFF_CAND   1024u     // 16*16384*8 = 2097152
#define OFF_DET    2098176u  // 16*1024*16 = 262144 (float4)
#define OFF_DETO   2360320u  // 262144
#define OFF_SCORE  2622464u  // 65536
#define OFF_LAB    2688000u  // 65536
#define OFF_VALID  2753536u  // 2048
#define OFF_COL    2755584u  // colsup: 16*1024*16*8 = 2097152
// total ~4.6 MB

__device__ __forceinline__ float sigm(float x) { return 1.0f / (1.0f + expf(-x)); }

// ---------------------------------------------------------------------------
// Single streaming pass. Grid 2048 x 256: block = (b = blk>>7, k = blk&127),
// owns rows [k*128, +128) = 2560 float4 = 40 KB of cls, contiguous.
// Survivors (exact score >= T0) staged in LDS; ONE global atomic per block.
// ---------------------------------------------------------------------------
__global__ __launch_bounds__(256) void k_pass1(const float* __restrict__ cls,
                                               const float* __restrict__ ctr,
                                               unsigned* __restrict__ cntp,
                                               unsigned long long* __restrict__ cand) {
    __shared__ float xh[128];    // conservative raw-logit threshold per row
    __shared__ float sbv[128];   // exact sigmoid(centerness) per row
    __shared__ unsigned long long stage[1024];
    __shared__ unsigned lcnt, gbase, lcw;
    const int blk = blockIdx.x, t = threadIdx.x;
    const int b = blk >> 7, k = blk & 127;
    if (t == 0) lcnt = 0;
    if (t < 128) {
        float sc = sigm(ctr[b * N_ + k * 128 + t]);
        sbv[t] = sc;
        float q = T0_ / sc;
        xh[t] = (q < 1.f) ? (logf(q / (1.f - q)) - 1e-3f) : 3.0e38f;
    }
    __syncthreads();
    const float4* p = (const float4*)(cls + (size_t)b * NC_ + (size_t)k * 10240);
    float4 a0 = p[t], a1 = p[256 + t];
    for (int it = 0; it < 5; ++it) {
        float4 n0 = {0,0,0,0}, n1 = {0,0,0,0};
        if (it < 4) { n0 = p[(it + 1) * 512 + t]; n1 = p[(it + 1) * 512 + 256 + t]; }
        #pragma unroll
        for (int h = 0; h < 2; ++h) {
            float4 v = h ? a1 : a0;
            int f = it * 512 + h * 256 + t;        // float4 index within chunk [0,2560)
            int nl = f / 20;                        // row (80 floats = 20 float4 per row)
            float thr = xh[nl];
            float mx = fmaxf(fmaxf(v.x, v.y), fmaxf(v.z, v.w));
            if (mx >= thr) {
                float sb = sbv[nl];
                float xs[4] = {v.x, v.y, v.z, v.w};
                #pragma unroll
                for (int j = 0; j < 4; ++j) {
                    if (xs[j] >= thr) {
                        float s = sigm(xs[j]);               // exact, matches reference
                        unsigned key = __float_as_uint(s * sb);
                        if (key >= T0KEY_) {                 // score >= 0.70 (implies conf mask)
                            unsigned pos = atomicAdd(&lcnt, 1u);
                            if (pos < 1024u) {
                                unsigned e = (unsigned)(k * 2560 + f) * 4u + (unsigned)j;
                                stage[pos] = ((unsigned long long)key << 32) |
                                             (unsigned long long)(0xFFFFFFFFu - e);
                            }
                        }
                    }
                }
            }
        }
        a0 = n0; a1 = n1;
    }
    __syncthreads();
    if (t == 0) {
        unsigned lc = lcnt; if (lc > 1024u) { lc = 1024u; cntp[b * 16 + 1] = 1u; }
        gbase = atomicAdd(&cntp[b * 16], lc);
        lcw = lc;
    }
    __syncthreads();
    for (unsigned i = t; i < lcw; i += 256) {
        unsigned gp = gbase + i;
        if (gp < CAP2_) cand[(size_t)b * CAP2_ + gp] = stage[i];
    }
}

// ---------------------------------------------------------------------------
// Rescue (always launched; early-exits when cnt>=1000). Appends survivors with
// key in [0.25, 0.70) for under-filled batches.
// ---------------------------------------------------------------------------
__global__ __launch_bounds__(256) void k_rescue(const float* __restrict__ cls,
                                                const float* __restrict__ ctr,
                                                unsigned* __restrict__ cntp,
                                                unsigned long long* __restrict__ cand) {
    const int blk = blockIdx.x, t = threadIdx.x;
    const int b = blk >> 7, k = blk & 127;
    if (cntp[b * 16] >= (unsigned)TOPN_) return;     // common case: done
    __shared__ float xh[128];
    __shared__ float sbv[128];
    __shared__ unsigned long long stage[1024];
    __shared__ unsigned lcnt, gbase, lcw;
    if (t == 0) lcnt = 0;
    if (t < 128) {
        float sc = sigm(ctr[b * N_ + k * 128 + t]);
        sbv[t] = sc;
        float q = 0.25f / sc;
        xh[t] = (q < 1.f) ? (logf(q / (1.f - q)) - 1e-3f) : 3.0e38f;
    }
    __syncthreads();
    const float4* p = (const float4*)(cls + (size_t)b * NC_ + (size_t)k * 10240);
    for (int f = t; f < 2560; f += 256) {
        float4 v = p[f];
        int nl = f / 20;
        float thr = xh[nl];
        float mx = fmaxf(fmaxf(v.x, v.y), fmaxf(v.z, v.w));
        if (mx >= thr) {
            float sb = sbv[nl];
            float xs[4] = {v.x, v.y, v.z, v.w};
            #pragma unroll
            for (int j = 0; j < 4; ++j) {
                if (xs[j] >= thr) {
                    float s = sigm(xs[j]);
                    if (s > 0.05f) {
                        unsigned key = __float_as_uint(s * sb);
                        if (key >= RKEY_ && key < T0KEY_) {   // not already collected
                            unsigned pos = atomicAdd(&lcnt, 1u);
                            if (pos < 1024u) {
                                unsigned e = (unsigned)(k * 2560 + f) * 4u + (unsigned)j;
                                stage[pos] = ((unsigned long long)key << 32) |
                                             (unsigned long long)(0xFFFFFFFFu - e);
                            }
                        }
                    }
                }
            }
        }
    }
    __syncthreads();
    if (t == 0) {
        unsigned lc = lcnt; if (lc > 1024u) lc = 1024u;
        gbase = atomicAdd(&cntp[b * 16], lc);
        lcw = lc;
    }
    __syncthreads();
    for (unsigned i = t; i < lcw; i += 256) {
        unsigned gp = gbase + i;
        if (gp < CAP2_) cand[(size_t)b * CAP2_ + gp] = stage[i];
    }
}

// ---------------------------------------------------------------------------
// Per-batch select: histogram -> wave-parallel suffix-scan cutoff -> compact
// -> rank-based ordering (one barrier, broadcast reads) -> decode top-1024.
// One block (1024 thr) per batch.
// ---------------------------------------------------------------------------
__global__ __launch_bounds__(1024) void k_select(
        const unsigned long long* __restrict__ cand, const unsigned* __restrict__ cntp,
        const float* __restrict__ boxes, const float* __restrict__ locs,
        const int* __restrict__ ph, const int* __restrict__ pw,
        float4* __restrict__ det, float4* __restrict__ deto,
        float* __restrict__ score, int* __restrict__ lab,
        unsigned long long* __restrict__ validmask) {
    __shared__ unsigned hbin[NBIN_];
    __shared__ unsigned c1[1024];
    __shared__ unsigned long long srt[2048];
    __shared__ unsigned long long srt2[2048];
    __shared__ unsigned scnt, Lsh;
    const int b = blockIdx.x, t = threadIdx.x;
    unsigned c = cntp[b * 16]; if (c > CAP2_) c = CAP2_;
    for (int i = t; i < NBIN_; i += 1024) hbin[i] = 0;
    srt[t] = 0ull; srt[t + 1024] = 0ull;
    srt2[t] = 0ull; srt2[t + 1024] = 0ull;
    if (t == 0) scnt = 0;
    __syncthreads();
    const unsigned long long* g = cand + (size_t)b * CAP2_;
    for (unsigned i = t; i < c; i += 1024) {
        unsigned key = (unsigned)(g[i] >> 32);
        int bin = (int)(key >> 12) - (int)BASE12_;
        if (bin < 0) bin = 0; if (bin >= NBIN_) bin = NBIN_ - 1;
        atomicAdd(&hbin[bin], 1u);
    }
    __syncthreads();
    // c1[t] = sum of 4 contiguous bins
    {
        unsigned s = hbin[4 * t] + hbin[4 * t + 1] + hbin[4 * t + 2] + hbin[4 * t + 3];
        c1[t] = s;
    }
    __syncthreads();
    if (t < 64) {
        const int l = t;
        // chunk sum: 64 bins each (16 c1 entries)
        unsigned cs = 0;
        #pragma unroll
        for (int i = 0; i < 16; ++i) cs += c1[16 * l + i];
        // suffix scan (S_l = sum_{m>=l} cs_m)
        unsigned S = cs;
        #pragma unroll
        for (int off = 1; off < 64; off <<= 1) {
            unsigned y = __shfl_down(S, off, 64);
            if (l + off < 64) S += y;
        }
        unsigned long long m1 = __ballot(S >= (unsigned)TOPN_);
        unsigned Lval = RKEY_;                      // fallback: fewer than TOPN total
        if (m1) {
            int l1 = 63 - __builtin_clzll(m1);      // crossing chunk
            unsigned above = (l1 < 63) ? __shfl(S, l1 + 1, 64) : 0u;
            unsigned K2 = (unsigned)TOPN_ - above;
            // level 2: suffix scan over the 64 bins of chunk l1
            unsigned v2 = hbin[64 * l1 + l];
            unsigned S2 = v2;
            #pragma unroll
            for (int off = 1; off < 64; off <<= 1) {
                unsigned y = __shfl_down(S2, off, 64);
                if (l + off < 64) S2 += y;
            }
            unsigned long long m2 = __ballot(S2 >= K2);
            int l2 = 63 - __builtin_clzll(m2);      // guaranteed nonzero
            Lval = ((unsigned)BASE12_ + (unsigned)(64 * l1 + l2)) << 12;
        }
        if (l == 0) Lsh = Lval;
    }
    __syncthreads();
    unsigned L = Lsh;
    for (unsigned i = t; i < c; i += 1024) {
        unsigned long long comp = g[i];
        if ((unsigned)(comp >> 32) >= L) {
            unsigned pos = atomicAdd(&scnt, 1u);
            if (pos < 2048u) srt[pos] = comp;
        }
    }
    __syncthreads();
    unsigned sc_n = scnt; if (sc_n > 2048u) sc_n = 2048u;
    unsigned scR = (sc_n + 7u) & ~7u;               // srt zero-padded: safe
    // rank-based ordering: position = #{j : srt[j] > comp_i}; broadcast reads
    {
        unsigned long long e0 = srt[t], e1 = srt[t + 1024];
        unsigned r0 = 0, r1 = 0;
        for (unsigned j = 0; j < scR; j += 8) {
            #pragma unroll
            for (int u = 0; u < 8; ++u) {
                unsigned long long x = srt[j + u];
                r0 += (x > e0); r1 += (x > e1);
            }
        }
        __syncthreads();                             // (srt2 already zeroed)
        if ((unsigned)t < sc_n && e0) srt2[r0] = e0;
        if ((unsigned)(t + 1024) < sc_n && e1) srt2[r1] = e1;
    }
    __syncthreads();
    // decode rank t
    unsigned long long comp = srt2[t];
    unsigned key = (unsigned)(comp >> 32);
    float4 d = {0.f, 0.f, 0.f, 0.f}, doff = {0.f, 0.f, 0.f, 0.f};
    float sc = 0.f; int lb = 0;
    if (key) {
        unsigned idx = 0xFFFFFFFFu - (unsigned)comp;
        unsigned loc = idx / (unsigned)C_;
        unsigned cc = idx - loc * (unsigned)C_;
        lb = (int)cc + 1;
        float4 pb = ((const float4*)boxes)[(size_t)b * N_ + loc];
        float lx = locs[2 * loc], ly = locs[2 * loc + 1];
        float Wm1 = (float)(pw[0] - 1), Hm1 = (float)(ph[0] - 1);
        d.x = fminf(fmaxf(lx - pb.x, 0.f), Wm1);
        d.y = fminf(fmaxf(ly - pb.y, 0.f), Hm1);
        d.z = fminf(fmaxf(lx + pb.z, 0.f), Wm1);
        d.w = fminf(fmaxf(ly + pb.w, 0.f), Hm1);
        sc = __uint_as_float(key);
        float off = (float)lb * 4096.0f;
        doff.x = d.x + off; doff.y = d.y + off; doff.z = d.z + off; doff.w = d.w + off;
    }
    unsigned long long ball = __ballot(key != 0u);
    if ((t & 63) == 0) validmask[b * 16 + (t >> 6)] = ball;
    det[b * 1024 + t] = d;
    deto[b * 1024 + t] = doff;
    score[b * 1024 + t] = sc;
    lab[b * 1024 + t] = lb;
}

// ---------------------------------------------------------------------------
// Transposed suppression matrix: colsup[b][i][w] bit jj = box j=w*64+jj
// suppresses box i, i.e. (iou(i,j) > 0.6 && j < i). Only j<i computed.
// ---------------------------------------------------------------------------
__global__ void k_col(const float4* __restrict__ deto, unsigned long long* __restrict__ colsup) {
    __shared__ float4 bx[1024];
    const int b = blockIdx.y;
    for (int i = threadIdx.x; i < 1024; i += blockDim.x) bx[i] = deto[b * 1024 + i];
    __syncthreads();
    int t = threadIdx.x;               // 256 threads: 16 rows x 16 words
    int i = blockIdx.x * 16 + (t >> 4);
    int w = t & 15;
    int j0 = w * 64;
    unsigned long long m = 0;
    if (i < TOPN_ && j0 < i) {
        float4 A = bx[i];
        float aA = fmaxf(A.z - A.x, 0.f) * fmaxf(A.w - A.y, 0.f);
        int jmax = i - j0; if (jmax > 64) jmax = 64;
        #pragma unroll 4
        for (int jj = 0; jj < jmax; ++jj) {
            float4 Bv = bx[j0 + jj];
            float aB = fmaxf(Bv.z - Bv.x, 0.f) * fmaxf(Bv.w - Bv.y, 0.f);
            float ix1 = fmaxf(A.x, Bv.x), iy1 = fmaxf(A.y, Bv.y);
            float ix2 = fminf(A.z, Bv.z), iy2 = fminf(A.w, Bv.w);
            float inter = fmaxf(ix2 - ix1, 0.f) * fmaxf(iy2 - iy1, 0.f);
            float iou = inter / (aA + aB - inter + 1e-9f);
            if (iou > 0.6f) m |= (1ull << jj);
        }
    }
    colsup[((size_t)b * 1024 + i) * 16 + w] = m;
}

// ---------------------------------------------------------------------------
// NMS via column ballots: 16 groups of 64 processed serially; prior-group
// suppression lane-local from replicated kept words; intra-group resolve via
// iterated-finalization ballot loop. Wave 0 resolves; all threads write out.
// ---------------------------------------------------------------------------
__global__ __launch_bounds__(1024) void k_nmsout(
        const unsigned long long* __restrict__ colsup,
        const unsigned long long* __restrict__ validmask,
        const float4* __restrict__ det, const float* __restrict__ score,
        const int* __restrict__ lab, float* __restrict__ out) {
    __shared__ unsigned long long keepw[16];
    const int b = blockIdx.x, t = threadIdx.x;
    if (t < 64) {
        const int ii = t;
        const unsigned long long* Cb = colsup + (size_t)b * 16384;
        unsigned long long K[16];
        unsigned long long col[16], coln[16];
        #pragma unroll
        for (int w = 0; w < 16; ++w) col[w] = Cb[(size_t)ii * 16 + w];
        unsigned long long vword[16];
        #pragma unroll
        for (int g = 0; g < 16; ++g) vword[g] = validmask[b * 16 + g];
        #pragma unroll
        for (int g = 0; g < 16; ++g) {
            if (g < 15) {       // prefetch next group's columns (hide latency)
                #pragma unroll
                for (int w = 0; w < 16; ++w)
                    coln[w] = Cb[(size_t)((g + 1) * 64 + ii) * 16 + w];
            }
            unsigned long long supprior = 0;
            #pragma unroll
            for (int w = 0; w < 16; ++w) if (w < g) supprior |= K[w] & col[w];
            bool alive = (((vword[g] >> ii) & 1ull) != 0) && (supprior == 0);
            unsigned long long diag = col[g];   // intra-group suppressors (jj < ii)
            unsigned long long undec = __ballot(alive);
            unsigned long long kept = 0;
            while (undec) {
                bool meU = ((undec >> ii) & 1ull) != 0;
                bool supK = (kept & diag) != 0;     // suppressed by finalized-kept
                bool anyU = (undec & diag) != 0;    // potential suppressor undecided
                unsigned long long bkm = __ballot(meU && !supK && !anyU);
                unsigned long long brm = __ballot(meU && supK);
                kept |= bkm;
                undec &= ~(bkm | brm);
            }
            K[g] = kept;
            if (ii == 0) keepw[g] = kept;
            #pragma unroll
            for (int w = 0; w < 16; ++w) col[w] = coln[w];
        }
    }
    __syncthreads();
    if (t < TOPN_) {
        bool kp = ((keepw[t >> 6] >> (t & 63)) & 1ull) != 0;
        float4 d = det[b * 1024 + t];
        ((float4*)out)[(size_t)b * TOPN_ + t] = kp ? d : make_float4(0.f, 0.f, 0.f, 0.f);
        out[B_ * TOPN_ * 4 + b * TOPN_ + t] = kp ? score[b * 1024 + t] : 0.f;
        out[B_ * TOPN_ * 5 + b * TOPN_ + t] = kp ? (float)lab[b * 1024 + t] : 0.f;
    }
}

extern "C" void kernel_launch(void* const* d_in, const int* in_sizes, int n_in,
                              void* d_out, int out_size, void* d_ws, size_t ws_size,
                              hipStream_t stream) {
    (void)in_sizes; (void)n_in; (void)out_size; (void)ws_size;
    const float* locations = (const float*)d_in[0];   // (16384, 2)
    const float* pred_cls  = (const float*)d_in[1];   // (16, 128, 128, 80)
    const float* pred_box  = (const float*)d_in[2];   // (16, 128, 128, 4)
    const float* pred_ctr  = (const float*)d_in[3];   // (16, 128, 128)
    const int*   ph        = (const int*)d_in[4];     // 1024
    const int*   pw        = (const int*)d_in[5];     // 1024
    float* out = (float*)d_out;

    char* w = (char*)d_ws;
    unsigned* cntp               = (unsigned*)(w + OFF_CNT);
    unsigned long long* cand     = (unsigned long long*)(w + OFF_CAND);
    float4* det                  = (float4*)(w + OFF_DET);
    float4* deto                 = (float4*)(w + OFF_DETO);
    float* score                 = (float*)(w + OFF_SCORE);
    int* lab                     = (int*)(w + OFF_LAB);
    unsigned long long* validmsk = (unsigned long long*)(w + OFF_VALID);
    unsigned long long* colsup   = (unsigned long long*)(w + OFF_COL);

    hipMemsetAsync(w, 0, ZERO_BYTES, stream);   // padded counters only

    k_pass1<<<2048, 256, 0, stream>>>(pred_cls, pred_ctr, cntp, cand);
    k_rescue<<<2048, 256, 0, stream>>>(pred_cls, pred_ctr, cntp, cand);
    k_select<<<B_, 1024, 0, stream>>>(cand, cntp, pred_box, locations, ph, pw,
                                      det, deto, score, lab, validmsk);
    k_col<<<dim3(64, B_), 256, 0, stream>>>(deto, colsup);
    k_nmsout<<<B_, 1024, 0, stream>>>(colsup, validmsk, det, score, lab, out);
}